// Round 6
// baseline (1070.168 us; speedup 1.0000x reference)
//
#include <hip/hip_runtime.h>

typedef __attribute__((ext_vector_type(8))) __bf16 bf16x8;
typedef __attribute__((ext_vector_type(8))) unsigned short u16x8;
typedef __attribute__((ext_vector_type(4))) unsigned short u16x4;
typedef __attribute__((ext_vector_type(2))) unsigned int u32x2;
typedef __attribute__((ext_vector_type(4))) float f32x4;
typedef unsigned short u16;
typedef unsigned int u32;

#define TSEQ 2064   /* 16 groups * 129 tokens (incl relay) per batch */
#define NTOK 4128   /* 2 batches * TSEQ */

__device__ __forceinline__ float bf2f(u16 u) {
  unsigned x = ((unsigned)u) << 16;
  return __builtin_bit_cast(float, x);
}
__device__ __forceinline__ u16 f2bf(float f) {
  unsigned u = __builtin_bit_cast(unsigned, f);
  u += 0x7fffu + ((u >> 16) & 1u);     // round-to-nearest-even
  return (u16)(u >> 16);
}

// async 16B global->LDS (linear dest = wave-uniform base + lane*16)
__device__ __forceinline__ void gll16(const u16* g, u16* l) {
  __builtin_amdgcn_global_load_lds((const __attribute__((address_space(1))) void*)g,
                                   (__attribute__((address_space(3))) void*)l, 16, 0, 0);
}
// XOR swizzle within a 64-element (128B) row: spreads 8 rows over 8 16B slots
__device__ __forceinline__ int swz(int row, int col) {
  return row * 64 + (col ^ ((row & 7) << 3));
}

// ---------------- all weight transposes in ONE launch ----------------------
// (L,K,N) -> (L,N,K), f32 -> bf16
__global__ __launch_bounds__(256) void transpose_all(
    const float* __restrict__ s0, const float* __restrict__ s1,
    const float* __restrict__ s2, const float* __restrict__ s3,
    const float* __restrict__ s4, const float* __restrict__ s5,
    u16* __restrict__ d0, u16* __restrict__ d1, u16* __restrict__ d2,
    u16* __restrict__ d3, u16* __restrict__ d4, u16* __restrict__ d5)
{
  __shared__ float tile[32][33];
  int bid = blockIdx.x;
  const float* src; u16* dst; int K, N, r;
  if (bid < 6144)       { r = bid - (bid >= 3072 ? 3072 : 0);
                          K = 512; N = 1536; src = bid >= 3072 ? s1 : s0; dst = bid >= 3072 ? d1 : d0; }
  else if (bid < 8192)  { r = bid - (bid >= 7168 ? 7168 : 6144);
                          K = 512; N = 512;  src = bid >= 7168 ? s3 : s2; dst = bid >= 7168 ? d3 : d2; }
  else if (bid < 12288) { r = bid - 8192;  K = 512;  N = 2048; src = s4; dst = d4; }
  else                  { r = bid - 12288; K = 2048; N = 512;  src = s5; dst = d5; }
  const int tx = N >> 5, per = tx * (K >> 5);
  const int l = r / per; r -= l * per;
  const int n0 = (r % tx) * 32, k0 = (r / tx) * 32;
  src += (size_t)l * K * N;
  dst += (size_t)l * K * N;
  const int c = threadIdx.x & 31, rr0 = threadIdx.x >> 5;
#pragma unroll
  for (int rr = rr0; rr < 32; rr += 8)
    tile[rr][c] = src[(size_t)(k0 + rr) * N + n0 + c];
  __syncthreads();
#pragma unroll
  for (int rr = rr0; rr < 32; rr += 8)
    dst[(size_t)(n0 + rr) * K + k0 + c] = f2bf(tile[c][rr]);
}

// ---------------- assemble working sequence with relay tokens --------------
__global__ void build_x(const float* __restrict__ xin, const float* __restrict__ relay,
                        float* __restrict__ xw)
{
  const int total = 2 * TSEQ * 512;
  for (int idx = blockIdx.x * 256 + threadIdx.x; idx < total; idx += gridDim.x * 256) {
    int col = idx & 511;
    int tok = (idx >> 9) % TSEQ;
    int b   = idx / (TSEQ * 512);
    int g = tok / 129, s = tok % 129;
    float v = (s == 0) ? relay[col]
                       : xin[((size_t)b * 2048 + g * 128 + (s - 1)) * 512 + col];
    xw[idx] = v;
  }
}

__global__ void extract_out(const float* __restrict__ xw, float* __restrict__ out)
{
  const int total = 2 * 2048 * 512;
  for (int idx = blockIdx.x * 256 + threadIdx.x; idx < total; idx += gridDim.x * 256) {
    int col = idx & 511;
    int tok = (idx >> 9) & 2047;
    int b   = idx / (2048 * 512);
    int g = tok >> 7, s = tok & 127;
    out[idx] = xw[((size_t)b * TSEQ + g * 129 + s + 1) * 512 + col];
  }
}

// ---------------- layernorm: f32 in -> bf16 out ----------------------------
__global__ __launch_bounds__(256) void ln_kernel(const float* __restrict__ x,
                                                 const float* __restrict__ g,
                                                 const float* __restrict__ bta,
                                                 u16* __restrict__ y, int M)
{
  const int wid = threadIdx.x >> 6, lane = threadIdx.x & 63;
  const int row = blockIdx.x * 4 + wid;
  if (row >= M) return;
  const float* xr = x + (size_t)row * 512;
  float v[8];
  float s = 0.f;
#pragma unroll
  for (int j = 0; j < 8; ++j) { v[j] = xr[j * 64 + lane]; s += v[j]; }
#pragma unroll
  for (int m = 1; m <= 32; m <<= 1) s += __shfl_xor(s, m);
  float mean = s * (1.f / 512.f);
  float vs = 0.f;
#pragma unroll
  for (int j = 0; j < 8; ++j) { float d = v[j] - mean; vs += d * d; }
#pragma unroll
  for (int m = 1; m <= 32; m <<= 1) vs += __shfl_xor(vs, m);
  float rstd = rsqrtf(vs * (1.f / 512.f) + 1e-5f);
  u16* yr = y + (size_t)row * 512;
#pragma unroll
  for (int j = 0; j < 8; ++j) {
    int c = j * 64 + lane;
    yr[c] = f2bf((v[j] - mean) * rstd * g[c] + bta[c]);
  }
}

__device__ __forceinline__ int relay_tok(int r) {   // r in 0..31 -> token index
  return (r >> 4) * TSEQ + (r & 15) * 129;
}

// ---------------- bf16 MFMA GEMM v4: 2-phase dbuf + split-K + XCD chunk ----
// C = A(MxK) * Bt(NxK)^T. 128x128 tile, BK=64, 4 waves (2x2), 64x64/wave.
// grid (nrow, ncol, S); each z handles K-range [z*Kb, (z+1)*Kb).
// ATOMIC: f32 atomicAdd into outp (residual stream); bias added at z==0.
// VOUT: QKV epilogue (V cols -> transposed vg, Q cols pre-scaled by 0.125).
// RELAYA: A rows remapped to relay tokens. RELAYC: out += at relay tokens.
// SWZGRID: bijective XCD-chunked remap so one XCD owns a row-band x all cols.
template<bool HAS_BIAS, bool ACT, bool OUT_BF16, bool VOUT,
         bool RELAYA, bool RELAYC, bool ATOMIC, bool SWZGRID>
__global__ __launch_bounds__(256, 4) void gemm4(
    const u16* __restrict__ A, const u16* __restrict__ Bt,
    const float* __restrict__ bias, void* __restrict__ outp,
    u16* __restrict__ vgout, int M, int N, int K, int Kb)
{
  __shared__ __attribute__((aligned(16))) u16 As[2][128 * 64];
  __shared__ __attribute__((aligned(16))) u16 Bs[2][128 * 64];
  const int tid = threadIdx.x, lane = tid & 63, wid = tid >> 6;
  int brow, bcol;
  if (SWZGRID) {
    int nrow = gridDim.x, ncol = gridDim.y;
    int nb = nrow * ncol;
    int lin = blockIdx.y * nrow + blockIdx.x;   // HW dispatch order (x fastest)
    int q = nb >> 3, r = nb & 7;
    int xcd = lin & 7, i = lin >> 3;
    int wg = (xcd < r ? xcd * (q + 1) : r * (q + 1) + (xcd - r) * q) + i;
    brow = wg / ncol; bcol = wg % ncol;         // col fastest: row-band per XCD
  } else { brow = blockIdx.x; bcol = blockIdx.y; }
  const int row0 = brow * 128, col0 = bcol * 128;
  const int kbeg = blockIdx.z * Kb, kend = kbeg + Kb;
  const int wm = (wid >> 1) * 64, wn = (wid & 1) * 64;
  const int srow = tid >> 3, sseg = tid & 7;
  const int fr = lane & 15, g = lane >> 4;
  f32x4 acc[4][4];
#pragma unroll
  for (int m = 0; m < 4; ++m)
#pragma unroll
    for (int n = 0; n < 4; ++n) acc[m][n] = (f32x4)0.f;
  const u16* Bb = Bt + (size_t)col0 * K;

#define STAGE(buf, kk0)                                                        \
  {                                                                            \
    _Pragma("unroll")                                                          \
    for (int i = 0; i < 4; ++i) {                                              \
      int row = srow + i * 32, ss = sseg ^ (row & 7);                          \
      size_t arow = RELAYA ? (size_t)relay_tok(row & 31) : (size_t)(row0 + row); \
      gll16(A + arow * K + (kk0) + ss * 8, &As[buf][row * 64 + sseg * 8]);     \
      gll16(Bb + (size_t)row * K + (kk0) + ss * 8, &Bs[buf][row * 64 + sseg * 8]); \
    }                                                                          \
  }

  STAGE(0, kbeg);
  __syncthreads();                         // buf0 ready
  int cur = 0;
  for (int k0 = kbeg; k0 < kend; k0 += 64) {
    if (k0 + 64 < kend) STAGE(cur ^ 1, k0 + 64);   // issue next-tile loads first
    const u16* as_ = &As[cur][0];
    const u16* bs_ = &Bs[cur][0];
#pragma unroll
    for (int kk = 0; kk < 2; ++kk) {
      bf16x8 a[4], bb[4];
#pragma unroll
      for (int m = 0; m < 4; ++m) a[m] = *(const bf16x8*)&as_[swz(wm + m * 16 + fr, kk * 32 + g * 8)];
#pragma unroll
      for (int n = 0; n < 4; ++n) bb[n] = *(const bf16x8*)&bs_[swz(wn + n * 16 + fr, kk * 32 + g * 8)];
      __builtin_amdgcn_s_setprio(1);
#pragma unroll
      for (int m = 0; m < 4; ++m)
#pragma unroll
        for (int n = 0; n < 4; ++n)
          acc[m][n] = __builtin_amdgcn_mfma_f32_16x16x32_bf16(a[m], bb[n], acc[m][n], 0, 0, 0);
      __builtin_amdgcn_s_setprio(0);
    }
    __syncthreads();                       // stage done + readers done
    cur ^= 1;
  }
#undef STAGE

#pragma unroll
  for (int m = 0; m < 4; ++m) {
#pragma unroll
    for (int n = 0; n < 4; ++n) {
#pragma unroll
      for (int j = 0; j < 4; ++j) {
        int grow = row0 + wm + m * 16 + g * 4 + j;
        int gcol = col0 + wn + n * 16 + fr;
        if (grow < M) {
          float v = acc[m][n][j];
          if (HAS_BIAS && (!ATOMIC || blockIdx.z == 0)) v += bias[gcol];
          if (ACT) v = (v > 0.f) ? v : 0.01f * v;
          if (RELAYC) {                        // fused residual+scatter to ybuf
            u16* p = (u16*)outp + (size_t)relay_tok(grow) * 512 + gcol;
            *p = f2bf(v + bf2f(*p));
          } else if (VOUT && gcol >= 1024) {   // V region -> transposed vg only
            int hh = (gcol - 1024) >> 6, dd = gcol & 63;
            int bb2 = grow >= TSEQ;
            int tok = grow - bb2 * TSEQ;
            vgout[((size_t)((bb2 * 8 + hh) * 64 + dd)) * 2112 + tok] = f2bf(v);
          } else if (ATOMIC) {                 // split-K accumulate into f32 resid
            atomicAdd((float*)outp + (size_t)grow * N + gcol, v);
          } else if (OUT_BF16) {
            if (VOUT && gcol < 512) v *= 0.125f;   // pre-scale Q for attention
            ((u16*)outp)[(size_t)grow * N + gcol] = f2bf(v);
          } else {
            ((float*)outp)[(size_t)grow * N + gcol] = v;
          }
        }
      }
    }
  }
}

// ---------------- flash attention v4: BQ=128, 8 waves, defer-max -----------
// grid (17 q-tiles, 16 bh, 2 kv-halves); block 512 = 8 waves.
// Q pre-scaled by 0.125 in QKV epilogue. Writes unnormalized O partial (bf16)
// + (m,l) per row; fa_combine merges the two halves.
__global__ __launch_bounds__(512, 4) void flash_attn4(const u16* __restrict__ big,
                                                      const u16* __restrict__ vg,
                                                      u16* __restrict__ op0,
                                                      u16* __restrict__ op1,
                                                      float2* __restrict__ mlb)
{
  __shared__ __attribute__((aligned(16))) u16 Qs[128 * 64];  // Q, then 8x P-scratch
  __shared__ __attribute__((aligned(16))) u16 Ks[2][64 * 64];
  __shared__ __attribute__((aligned(16))) u16 Vs[2][64 * 64];
  const int tid = threadIdx.x, lane = tid & 63, wid = tid >> 6;
  const int qt = blockIdx.x, bh = blockIdx.y, z = blockIdx.z;
  const int b = bh >> 3, h = bh & 7;
  const int q0 = qt * 128;
  const int srow = tid >> 3, sseg = tid & 7;
  const int ktbeg = z * 17, ktend = z ? 33 : 17;

  const u16* kb = big + ((size_t)(b * TSEQ)) * 1536 + h * 64 + 512;
  const u16* vb = vg + (size_t)bh * 64 * 2112;
#pragma unroll
  for (int i = 0; i < 2; ++i) {
    int row = srow + i * 64;
    int grow = b * TSEQ + q0 + row; grow = grow < NTOK ? grow : NTOK - 1;
    int ss = sseg ^ (row & 7);
    gll16(big + (size_t)grow * 1536 + h * 64 + ss * 8, &Qs[row * 64 + sseg * 8]);
  }
  {
    int ss = sseg ^ (srow & 7);
    gll16(kb + (size_t)(ktbeg * 64 + srow) * 1536 + ss * 8, &Ks[0][srow * 64 + sseg * 8]);
    gll16(vb + (size_t)srow * 2112 + ktbeg * 64 + ss * 8, &Vs[0][srow * 64 + sseg * 8]);
  }
  __syncthreads();
  const int fr = lane & 15, g = lane >> 4;
  bf16x8 aq0 = *(const bf16x8*)&Qs[swz(wid * 16 + fr, g * 8)];
  bf16x8 aq1 = *(const bf16x8*)&Qs[swz(wid * 16 + fr, 32 + g * 8)];
  u16* Pw = &Qs[wid * 1024];   // wave-private 16x64 P scratch (overlays Q)

  f32x4 oacc[4];
#pragma unroll
  for (int nf = 0; nf < 4; ++nf) oacc[nf] = (f32x4)0.f;
  float mrow = -1e30f, lsum = 0.f;   // stats for q-row = fr (replicated over g)
  int cur = 0;

  for (int kt = ktbeg; kt < ktend; ++kt) {
    if (kt + 1 < ktend) {                    // prefetch next tile into buf^1
      int ss = sseg ^ (srow & 7);
      gll16(kb + (size_t)((kt + 1) * 64 + srow) * 1536 + ss * 8, &Ks[cur ^ 1][srow * 64 + sseg * 8]);
      gll16(vb + (size_t)srow * 2112 + (kt + 1) * 64 + ss * 8, &Vs[cur ^ 1][srow * 64 + sseg * 8]);
    }
    const u16* ks = &Ks[cur][0];
    const u16* vs = &Vs[cur][0];
    // S^T = K * Q^T : lane holds S[k = kt*64 + n*16 + g*4 + j][q = fr]
    f32x4 s[4];
    __builtin_amdgcn_s_setprio(1);
#pragma unroll
    for (int n = 0; n < 4; ++n) {
      int row = n * 16 + fr;
      bf16x8 ak0 = *(const bf16x8*)&ks[swz(row, g * 8)];
      bf16x8 ak1 = *(const bf16x8*)&ks[swz(row, 32 + g * 8)];
      f32x4 t = (f32x4)0.f;
      t = __builtin_amdgcn_mfma_f32_16x16x32_bf16(ak0, aq0, t, 0, 0, 0);
      t = __builtin_amdgcn_mfma_f32_16x16x32_bf16(ak1, aq1, t, 0, 0, 0);
      s[n] = t;
    }
    __builtin_amdgcn_s_setprio(0);
    if (kt == 32) {                          // only ragged tile needs masking
#pragma unroll
      for (int n = 0; n < 4; ++n) {
        int kbase = kt * 64 + n * 16 + g * 4;
#pragma unroll
        for (int j = 0; j < 4; ++j)
          if (kbase + j >= TSEQ) s[n][j] = -1e30f;
      }
    }
    // row max: 15 local + 2 shfl (replica-uniform per q-row)
    float mloc = s[0][0];
#pragma unroll
    for (int n = 0; n < 4; ++n)
#pragma unroll
      for (int j = 0; j < 4; ++j) mloc = fmaxf(mloc, s[n][j]);
    mloc = fmaxf(mloc, __shfl_xor(mloc, 16));
    mloc = fmaxf(mloc, __shfl_xor(mloc, 32));
    if (!__all(mloc <= mrow + 8.f)) {        // defer-max: rescale only on growth
      float nm = fmaxf(mrow, mloc);
      float sc = __expf(mrow - nm);
      mrow = nm;
      lsum *= sc;
      float s4[4];
#pragma unroll
      for (int j = 0; j < 4; ++j) s4[j] = __shfl(sc, g * 4 + j);
#pragma unroll
      for (int nf = 0; nf < 4; ++nf)
#pragma unroll
        for (int j = 0; j < 4; ++j) oacc[nf][j] *= s4[j];
    }
    // p = exp(s - mrow); truncation-pack pairs via v_perm
    float psum = 0.f;
#pragma unroll
    for (int n = 0; n < 4; ++n) {
      float p0 = __expf(s[n][0] - mrow), p1 = __expf(s[n][1] - mrow);
      float p2 = __expf(s[n][2] - mrow), p3 = __expf(s[n][3] - mrow);
      psum += (p0 + p1) + (p2 + p3);
      u32x2 pk;
      pk[0] = __builtin_amdgcn_perm(__builtin_bit_cast(u32, p1), __builtin_bit_cast(u32, p0), 0x07060302u);
      pk[1] = __builtin_amdgcn_perm(__builtin_bit_cast(u32, p3), __builtin_bit_cast(u32, p2), 0x07060302u);
      *(u32x2*)&Pw[swz(fr, n * 16 + g * 4)] = pk;
    }
    psum += __shfl_xor(psum, 16);
    psum += __shfl_xor(psum, 32);
    lsum += psum;
    // PV
    __builtin_amdgcn_s_setprio(1);
#pragma unroll
    for (int kc = 0; kc < 2; ++kc) {
      bf16x8 ap = *(const bf16x8*)&Pw[swz(fr, kc * 32 + g * 8)];
#pragma unroll
      for (int nf = 0; nf < 4; ++nf) {
        bf16x8 bv = *(const bf16x8*)&vs[swz(nf * 16 + fr, kc * 32 + g * 8)];
        oacc[nf] = __builtin_amdgcn_mfma_f32_16x16x32_bf16(ap, bv, oacc[nf], 0, 0, 0);
      }
    }
    __builtin_amdgcn_s_setprio(0);
    __syncthreads();                         // next tile staged; readers done
    cur ^= 1;
  }

  u16* op = z ? op1 : op0;
#pragma unroll
  for (int nf = 0; nf < 4; ++nf) {
#pragma unroll
    for (int j = 0; j < 4; ++j) {
      int row = q0 + wid * 16 + g * 4 + j;
      if (row < TSEQ)
        op[((size_t)(b * TSEQ + row)) * 512 + h * 64 + nf * 16 + fr] = f2bf(oacc[nf][j]);
    }
  }
  if (lane < 16) {
    int row = q0 + wid * 16 + fr;
    if (row < TSEQ)
      mlb[(size_t)(z * 16 + bh) * 2112 + row] = float2{mrow, lsum};
  }
}

// ---------------- merge the two KV-half partials ---------------------------
__global__ __launch_bounds__(256) void fa_combine(const u16* __restrict__ op0,
                                                  const u16* __restrict__ op1,
                                                  const float2* __restrict__ mlb,
                                                  u16* __restrict__ ob)
{
  int idx = blockIdx.x * 256 + threadIdx.x;   // NTOK*128 threads, 4 cols each
  int tok = idx >> 7;
  int c4 = (idx & 127) * 4;
  int b = tok >= TSEQ;
  int row = tok - b * TSEQ;
  int h = c4 >> 6;
  float2 ml0 = mlb[(size_t)(b * 8 + h) * 2112 + row];
  float2 ml1 = mlb[(size_t)(16 + b * 8 + h) * 2112 + row];
  float M = fmaxf(ml0.x, ml1.x);
  float a0 = __expf(ml0.x - M), a1 = __expf(ml1.x - M);
  float inv = 1.f / (ml0.y * a0 + ml1.y * a1);
  u16x4 v0 = *(const u16x4*)&op0[(size_t)tok * 512 + c4];
  u16x4 v1 = *(const u16x4*)&op1[(size_t)tok * 512 + c4];
  u16x4 o;
#pragma unroll
  for (int j = 0; j < 4; ++j)
    o[j] = f2bf((bf2f(v0[j]) * a0 + bf2f(v1[j]) * a1) * inv);
  *(u16x4*)&ob[(size_t)tok * 512 + c4] = o;
}

// ---------------- relay-token global attention (32 tokens total) -----------
__global__ __launch_bounds__(256) void global_attn(const u16* __restrict__ rqkv,
                                                   u16* __restrict__ ro)
{
  const int b = blockIdx.x >> 3, h = blockIdx.x & 7;
  __shared__ float q[16][64], k[16][64], v[16][64], s[16][16], p[16][16];
  const int tid = threadIdx.x;
  for (int idx = tid; idx < 1024; idx += 256) {
    int rr = idx >> 6, c = idx & 63;
    size_t base = (size_t)(b * 16 + rr) * 1536 + h * 64 + c;
    q[rr][c] = bf2f(rqkv[base]);
    k[rr][c] = bf2f(rqkv[base + 512]);
    v[rr][c] = bf2f(rqkv[base + 1024]);
  }
  __syncthreads();
  {
    int i = tid >> 4, j = tid & 15;
    float acc = 0.f;
#pragma unroll
    for (int d = 0; d < 64; ++d) acc += q[i][d] * k[j][d];
    s[i][j] = acc * 0.125f;
  }
  __syncthreads();
  if (tid < 16) {
    float mx = -1e30f;
#pragma unroll
    for (int j = 0; j < 16; ++j) mx = fmaxf(mx, s[tid][j]);
    float sum = 0.f;
#pragma unroll
    for (int j = 0; j < 16; ++j) { float e = __expf(s[tid][j] - mx); p[tid][j] = e; sum += e; }
    float iv = 1.f / sum;
#pragma unroll
    for (int j = 0; j < 16; ++j) p[tid][j] *= iv;
  }
  __syncthreads();
  for (int idx = tid; idx < 1024; idx += 256) {
    int rr = idx >> 6, c = idx & 63;
    float acc = 0.f;
#pragma unroll
    for (int j = 0; j < 16; ++j) acc += p[rr][j] * v[j][c];
    ro[(size_t)(b * 16 + rr) * 512 + h * 64 + c] = f2bf(acc);
  }
}

// ---------------------------------------------------------------------------
extern "C" void kernel_launch(void* const* d_in, const int* in_sizes, int n_in,
                              void* d_out, int out_size, void* d_ws, size_t ws_size,
                              hipStream_t stream)
{
  const float* x_in     = (const float*)d_in[0];
  const float* rel_emb  = (const float*)d_in[1];
  const float* ln1_g    = (const float*)d_in[2];
  const float* ln1_b    = (const float*)d_in[3];
  const float* loc_qkv  = (const float*)d_in[4];
  const float* loc_ow   = (const float*)d_in[5];
  const float* loc_ob   = (const float*)d_in[6];
  const float* glob_qkv = (const float*)d_in[7];
  const float* glob_ow  = (const float*)d_in[8];
  const float* glob_ob  = (const float*)d_in[9];
  const float* ln2_g    = (const float*)d_in[10];
  const float* ln2_b    = (const float*)d_in[11];
  const float* ff_w1    = (const float*)d_in[12];
  const float* ff_b1    = (const float*)d_in[13];
  const float* ff_w2    = (const float*)d_in[14];
  const float* ff_b2    = (const float*)d_in[15];

  char* ws = (char*)d_ws;
  float*  xbuf = (float*)(ws + 0);             // f32 [4224][512]   8,650,752
  u16*    ybuf = (u16*)(ws + 8650752);         // bf16 [4224][512]  (LN out; flash O-partial 0)
  u16*    obuf = (u16*)(ws + 12976128);        // bf16 [4224][512]  (flash O-partial 1 / combined)
  u16*    big  = (u16*)(ws + 17301504);        // bf16 [4224][2048] 17,301,504
  u16*    vg   = (u16*)(ws + 34603008);        // bf16 [16*64][2112] 4,325,376
  u16*    wLQ  = (u16*)(ws + 38928384);        // 4x1536x512  6,291,456
  u16*    wGQ  = (u16*)(ws + 45219840);        // 6,291,456
  u16*    wLO  = (u16*)(ws + 51511296);        // 4x512x512   2,097,152
  u16*    wGO  = (u16*)(ws + 53608448);        // 2,097,152
  u16*    wF1  = (u16*)(ws + 55705600);        // 4x2048x512  8,388,608
  u16*    wF2  = (u16*)(ws + 64094208);        // 4x512x2048  8,388,608
  u16*    rqkv = (u16*)(ws + 72482816);        // 32x1536     98,304
  u16*    rov  = (u16*)(ws + 72581120);        // [128][512] bf16 131,072
  float2* mlb  = (float2*)(ws + 72712192);     // [2][16][2112] float2 540,672 (end 73,252,864)

  dim3 B(256);
  transpose_all<<<16384, B, 0, stream>>>(loc_qkv, glob_qkv, loc_ow, glob_ow, ff_w1, ff_w2,
                                         wLQ, wGQ, wLO, wGO, wF1, wF2);
  build_x<<<8256, B, 0, stream>>>(x_in, rel_emb, xbuf);

  for (int l = 0; l < 4; ++l) {
    ln_kernel<<<1032, B, 0, stream>>>(xbuf, ln1_g + l * 512, ln1_b + l * 512, ybuf, NTOK);
    if (l + 1 >= 2) {
      gemm4<false, false, true, false, true, false, false, false><<<dim3(1, 12, 1), B, 0, stream>>>(
          ybuf, wGQ + (size_t)l * 1536 * 512, nullptr, rqkv, nullptr, 32, 1536, 512, 512);
      global_attn<<<16, B, 0, stream>>>(rqkv, rov);
      gemm4<true, false, true, false, false, true, false, false><<<dim3(1, 4, 1), B, 0, stream>>>(
          rov, wGO + (size_t)l * 512 * 512, glob_ob + l * 512, ybuf, nullptr, 32, 512, 512, 512);
    }
    gemm4<false, false, true, true, false, false, false, true><<<dim3(33, 12, 1), B, 0, stream>>>(
        ybuf, wLQ + (size_t)l * 1536 * 512, nullptr, big, vg, NTOK, 1536, 512, 512);
    flash_attn4<<<dim3(17, 16, 2), dim3(512), 0, stream>>>(big, vg, ybuf, obuf, mlb);
    fa_combine<<<2064, B, 0, stream>>>(ybuf, obuf, mlb, obuf);
    gemm4<true, false, false, false, false, false, true, true><<<dim3(33, 4, 4), B, 0, stream>>>(
        obuf, wLO + (size_t)l * 512 * 512, loc_ob + l * 512, xbuf, nullptr, NTOK, 512, 512, 128);
    ln_kernel<<<1032, B, 0, stream>>>(xbuf, ln2_g + l * 512, ln2_b + l * 512, ybuf, NTOK);
    gemm4<true, true, true, false, false, false, false, true><<<dim3(33, 16, 1), B, 0, stream>>>(
        ybuf, wF1 + (size_t)l * 2048 * 512, ff_b1 + l * 2048, big, nullptr, NTOK, 2048, 512, 512);
    gemm4<true, false, false, false, false, false, true, true><<<dim3(33, 4, 4), B, 0, stream>>>(
        big, wF2 + (size_t)l * 512 * 2048, ff_b2 + l * 512, xbuf, nullptr, NTOK, 512, 2048, 512);
  }
  extract_out<<<8192, B, 0, stream>>>(xbuf, (float*)d_out);
}